// Round 1
// baseline (451.488 us; speedup 1.0000x reference)
//
#include <hip/hip_runtime.h>

// GCN 2-layer forward for MI355X.
// Pipeline (all on `stream`, graph-capture safe):
//   1. zero indeg/cursor
//   2. histogram in-degree (int atomics)
//   3. dinv[n] = 1/sqrt(indeg+1)   (self-loop included)
//   4-6. exclusive scan of indeg -> row_start (CSR offsets)
//   7. scatter edges into CSR (int atomics), norm = dinv[src]*dinv[dst]
//   8. GEMM1: h0 = x @ W1           (fp32 tiled, LDS)
//   9. agg1: h1 = relu(Ahat*h0 + b1)  pull-style, no float atomics
//  10. GEMM2: h2 = h1 @ W2
//  11. agg2: out = Ahat*h2 + b2

#define NNODES 50000
#define NEDGES 640000
#define NFEAT 512
#define NHID 128
#define NCLS 64

__global__ void k_zero2(int* __restrict__ a, int* __restrict__ b, int n) {
  int i = blockIdx.x * blockDim.x + threadIdx.x;
  if (i < n) { a[i] = 0; b[i] = 0; }
}

__global__ void k_hist(const int* __restrict__ dst, int* __restrict__ indeg, int E) {
  int i = blockIdx.x * blockDim.x + threadIdx.x;
  if (i < E) atomicAdd(&indeg[dst[i]], 1);
}

__global__ void k_dinv(const int* __restrict__ indeg, float* __restrict__ dinv, int n) {
  int i = blockIdx.x * blockDim.x + threadIdx.x;
  if (i < n) dinv[i] = 1.0f / sqrtf((float)(indeg[i] + 1));
}

// Block-level exclusive scan: 256 threads x 4 elems = 1024/block
__global__ void k_scan_block(const int* __restrict__ indeg, int* __restrict__ row_start,
                             int* __restrict__ blocksum, int n) {
  __shared__ int sdata[256];
  int t = threadIdx.x;
  int base = blockIdx.x * 1024 + t * 4;
  int v[4];
#pragma unroll
  for (int j = 0; j < 4; ++j) v[j] = (base + j < n) ? indeg[base + j] : 0;
  int tsum = v[0] + v[1] + v[2] + v[3];
  sdata[t] = tsum;
  __syncthreads();
  for (int off = 1; off < 256; off <<= 1) {
    int x = (t >= off) ? sdata[t - off] : 0;
    __syncthreads();
    sdata[t] += x;
    __syncthreads();
  }
  int excl = sdata[t] - tsum;
  if (t == 255) blocksum[blockIdx.x] = sdata[255];
  int run = excl;
#pragma unroll
  for (int j = 0; j < 4; ++j) {
    if (base + j < n) { row_start[base + j] = run; run += v[j]; }
  }
}

__global__ void k_scan_top(const int* __restrict__ blocksum, int* __restrict__ blockoff, int nb) {
  if (threadIdx.x == 0 && blockIdx.x == 0) {
    int run = 0;
    for (int i = 0; i < nb; ++i) { blockoff[i] = run; run += blocksum[i]; }
  }
}

__global__ void k_scan_add(int* __restrict__ row_start, const int* __restrict__ blockoff,
                           int n, int E) {
  int i = blockIdx.x * blockDim.x + threadIdx.x;
  if (i < n) row_start[i] += blockoff[i >> 10];
  if (i == 0) row_start[n] = E;
}

__global__ void k_scatter(const int* __restrict__ src, const int* __restrict__ dst,
                          const int* __restrict__ row_start, int* __restrict__ cursor,
                          const float* __restrict__ dinv, int* __restrict__ csr_src,
                          float* __restrict__ csr_norm, int E) {
  int e = blockIdx.x * blockDim.x + threadIdx.x;
  if (e < E) {
    int s = src[e], d = dst[e];
    int pos = atomicAdd(&cursor[d], 1);
    int idx = row_start[d] + pos;
    csr_src[idx] = s;
    csr_norm[idx] = dinv[s] * dinv[d];
  }
}

// C[M][BN] = A[M][K] @ B[K][BN].  One block covers BM rows x all BN cols.
// 256 threads; each thread: 4 rows x (4*SLABS) cols.
template <int BM, int BN, int BK, int SLABS>
__global__ __launch_bounds__(256) void k_gemm(const float* __restrict__ A,
                                              const float* __restrict__ B,
                                              float* __restrict__ C, int M, int K) {
  constexpr int TXN = BN / (4 * SLABS);       // # thread-cols
  constexpr int SLAB_STRIDE = BN / SLABS;
  __shared__ float As[BK][BM];                // transposed A tile
  __shared__ float Bs[BK][BN];
  const int tid = threadIdx.x;
  const int tx = tid % TXN;
  const int ty = tid / TXN;
  const int row0 = blockIdx.x * BM;

  float acc[4][4 * SLABS];
#pragma unroll
  for (int i = 0; i < 4; ++i)
#pragma unroll
    for (int j = 0; j < 4 * SLABS; ++j) acc[i][j] = 0.f;

  for (int k0 = 0; k0 < K; k0 += BK) {
    // ---- load A tile (coalesced float4 along K, transpose into As[k][m]) ----
    constexpr int A_F4 = BM * BK / 4;         // float4 count
#pragma unroll
    for (int it = 0; it < A_F4 / 256; ++it) {
      int v = tid + it * 256;
      int m = v / (BK / 4);
      int kq = v % (BK / 4);
      float4 val;
      if (row0 + m < M)
        val = *(const float4*)(A + (size_t)(row0 + m) * K + k0 + kq * 4);
      else
        val = make_float4(0.f, 0.f, 0.f, 0.f);
      As[kq * 4 + 0][m] = val.x;
      As[kq * 4 + 1][m] = val.y;
      As[kq * 4 + 2][m] = val.z;
      As[kq * 4 + 3][m] = val.w;
    }
    // ---- load B tile (row-major, coalesced) ----
    constexpr int B_F4 = BK * BN / 4;
#pragma unroll
    for (int it = 0; it < B_F4 / 256; ++it) {
      int v = tid + it * 256;
      int kb = v / (BN / 4);
      int nq = v % (BN / 4);
      *(float4*)&Bs[kb][nq * 4] = *(const float4*)(B + (size_t)(k0 + kb) * BN + nq * 4);
    }
    __syncthreads();

#pragma unroll
    for (int kk = 0; kk < BK; ++kk) {
      float4 a4 = *(const float4*)&As[kk][ty * 4];
      float av[4] = {a4.x, a4.y, a4.z, a4.w};
#pragma unroll
      for (int s = 0; s < SLABS; ++s) {
        float4 b4 = *(const float4*)&Bs[kk][s * SLAB_STRIDE + tx * 4];
        float bv[4] = {b4.x, b4.y, b4.z, b4.w};
#pragma unroll
        for (int i = 0; i < 4; ++i)
#pragma unroll
          for (int j = 0; j < 4; ++j) acc[i][s * 4 + j] += av[i] * bv[j];
      }
    }
    __syncthreads();
  }

#pragma unroll
  for (int i = 0; i < 4; ++i) {
    int r = row0 + ty * 4 + i;
    if (r < M) {
#pragma unroll
      for (int s = 0; s < SLABS; ++s) {
        float4 o;
        o.x = acc[i][s * 4 + 0];
        o.y = acc[i][s * 4 + 1];
        o.z = acc[i][s * 4 + 2];
        o.w = acc[i][s * 4 + 3];
        *(float4*)(C + (size_t)r * BN + s * SLAB_STRIDE + tx * 4) = o;
      }
    }
  }
}

// Pull-style aggregation: out[n][f] = (opt relu)( bias[f] + dinv[n]^2*h[n][f]
//                                      + sum_e norm[e]*h[csr_src[e]][f] )
template <int F, bool RELU>
__global__ __launch_bounds__(F) void k_agg(const float* __restrict__ h,
                                           const float* __restrict__ bias,
                                           const int* __restrict__ row_start,
                                           const int* __restrict__ csr_src,
                                           const float* __restrict__ csr_norm,
                                           const float* __restrict__ dinv,
                                           float* __restrict__ out) {
  int n = blockIdx.x;
  int f = threadIdx.x;
  float dn = dinv[n];
  float acc = dn * dn * h[n * F + f];
  int e0 = row_start[n], e1 = row_start[n + 1];
  for (int e = e0; e < e1; ++e) {
    int s = csr_src[e];
    float w = csr_norm[e];
    acc += w * h[s * F + f];
  }
  acc += bias[f];
  if (RELU) acc = fmaxf(acc, 0.f);
  out[n * F + f] = acc;
}

static inline size_t align256(size_t x) { return (x + 255) & ~(size_t)255; }

extern "C" void kernel_launch(void* const* d_in, const int* in_sizes, int n_in,
                              void* d_out, int out_size, void* d_ws, size_t ws_size,
                              hipStream_t stream) {
  const float* x = (const float*)d_in[0];
  const int* edge = (const int*)d_in[1];
  const float* W1 = (const float*)d_in[2];
  const float* b1 = (const float*)d_in[3];
  const float* W2 = (const float*)d_in[4];
  const float* b2 = (const float*)d_in[5];
  float* out = (float*)d_out;

  const int N = NNODES;
  const int E = NEDGES;
  const int* src = edge;
  const int* dst = edge + E;

  // workspace carve-up
  char* w = (char*)d_ws;
  int* indeg = (int*)w;            w += align256((size_t)N * 4);
  int* cursor = (int*)w;           w += align256((size_t)N * 4);
  float* dinv = (float*)w;         w += align256((size_t)N * 4);
  int* row_start = (int*)w;        w += align256((size_t)(N + 1) * 4);
  int* blocksum = (int*)w;         w += align256(64 * 4);
  int* blockoff = (int*)w;         w += align256(64 * 4);
  int* csr_src = (int*)w;          w += align256((size_t)E * 4);
  float* csr_norm = (float*)w;     w += align256((size_t)E * 4);
  float* h0 = (float*)w;           w += align256((size_t)N * NHID * 4);
  float* h1 = (float*)w;           w += align256((size_t)N * NHID * 4);
  float* h2 = (float*)w;           w += align256((size_t)N * NCLS * 4);

  const int nblk_n = (N + 255) / 256;       // 196
  const int nblk_e = (E + 255) / 256;       // 2500
  const int nblk_scan = (N + 1023) / 1024;  // 49

  k_zero2<<<nblk_n, 256, 0, stream>>>(indeg, cursor, N);
  k_hist<<<nblk_e, 256, 0, stream>>>(dst, indeg, E);
  k_dinv<<<nblk_n, 256, 0, stream>>>(indeg, dinv, N);
  k_scan_block<<<nblk_scan, 256, 0, stream>>>(indeg, row_start, blocksum, N);
  k_scan_top<<<1, 64, 0, stream>>>(blocksum, blockoff, nblk_scan);
  k_scan_add<<<nblk_n, 256, 0, stream>>>(row_start, blockoff, N, E);
  k_scatter<<<nblk_e, 256, 0, stream>>>(src, dst, row_start, cursor, dinv,
                                        csr_src, csr_norm, E);

  // GEMM1: h0 = x @ W1   (50000x512 @ 512x128)
  k_gemm<64, NHID, 32, 2><<<(N + 63) / 64, 256, 0, stream>>>(x, W1, h0, N, NFEAT);
  // agg1: h1 = relu(Ahat*h0 + b1)
  k_agg<NHID, true><<<N, NHID, 0, stream>>>(h0, b1, row_start, csr_src, csr_norm,
                                            dinv, h1);
  // GEMM2: h2 = h1 @ W2   (50000x128 @ 128x64)
  k_gemm<64, NCLS, 32, 1><<<(N + 63) / 64, 256, 0, stream>>>(h1, W2, h2, N, NHID);
  // agg2: out = Ahat*h2 + b2
  k_agg<NCLS, false><<<N, NCLS, 0, stream>>>(h2, b2, row_start, csr_src, csr_norm,
                                             dinv, out);
}

// Round 2
// 428.085 us; speedup vs baseline: 1.0547x; 1.0547x over previous
//
#include <hip/hip_runtime.h>

// GCN 2-layer forward for MI355X.
// R2: GEMM 8x8/thread 2x2-slab fp32 (padded-LDS transpose), agg edge-unroll x4.

#define NNODES 50000
#define NEDGES 640000
#define NFEAT 512
#define NHID 128
#define NCLS 64

__global__ void k_zero2(int* __restrict__ a, int* __restrict__ b, int n) {
  int i = blockIdx.x * blockDim.x + threadIdx.x;
  if (i < n) { a[i] = 0; b[i] = 0; }
}

__global__ void k_hist(const int* __restrict__ dst, int* __restrict__ indeg, int E) {
  int i = blockIdx.x * blockDim.x + threadIdx.x;
  if (i < E) atomicAdd(&indeg[dst[i]], 1);
}

__global__ void k_dinv(const int* __restrict__ indeg, float* __restrict__ dinv, int n) {
  int i = blockIdx.x * blockDim.x + threadIdx.x;
  if (i < n) dinv[i] = 1.0f / sqrtf((float)(indeg[i] + 1));
}

// Block-level exclusive scan: 256 threads x 4 elems = 1024/block
__global__ void k_scan_block(const int* __restrict__ indeg, int* __restrict__ row_start,
                             int* __restrict__ blocksum, int n) {
  __shared__ int sdata[256];
  int t = threadIdx.x;
  int base = blockIdx.x * 1024 + t * 4;
  int v[4];
#pragma unroll
  for (int j = 0; j < 4; ++j) v[j] = (base + j < n) ? indeg[base + j] : 0;
  int tsum = v[0] + v[1] + v[2] + v[3];
  sdata[t] = tsum;
  __syncthreads();
  for (int off = 1; off < 256; off <<= 1) {
    int x = (t >= off) ? sdata[t - off] : 0;
    __syncthreads();
    sdata[t] += x;
    __syncthreads();
  }
  int excl = sdata[t] - tsum;
  if (t == 255) blocksum[blockIdx.x] = sdata[255];
  int run = excl;
#pragma unroll
  for (int j = 0; j < 4; ++j) {
    if (base + j < n) { row_start[base + j] = run; run += v[j]; }
  }
}

__global__ void k_scan_top(const int* __restrict__ blocksum, int* __restrict__ blockoff, int nb) {
  if (threadIdx.x == 0 && blockIdx.x == 0) {
    int run = 0;
    for (int i = 0; i < nb; ++i) { blockoff[i] = run; run += blocksum[i]; }
  }
}

__global__ void k_scan_add(int* __restrict__ row_start, const int* __restrict__ blockoff,
                           int n, int E) {
  int i = blockIdx.x * blockDim.x + threadIdx.x;
  if (i < n) row_start[i] += blockoff[i >> 10];
  if (i == 0) row_start[n] = E;
}

__global__ void k_scatter(const int* __restrict__ src, const int* __restrict__ dst,
                          const int* __restrict__ row_start, int* __restrict__ cursor,
                          const float* __restrict__ dinv, int* __restrict__ csr_src,
                          float* __restrict__ csr_norm, int E) {
  int e = blockIdx.x * blockDim.x + threadIdx.x;
  if (e < E) {
    int s = src[e], d = dst[e];
    int pos = atomicAdd(&cursor[d], 1);
    int idx = row_start[d] + pos;
    csr_src[idx] = s;
    csr_norm[idx] = dinv[s] * dinv[d];
  }
}

// C[M][BN] = A[M][K] @ B[K][BN], BN == full N (B tile contiguous).
// 128 threads; each thread 8x8 outputs in 2x2 slabs (rows {ty*4, BM/2+ty*4},
// cols {tx*4, BN/2+tx*4}). As padded to BM+4: float4 reads stay 16B-aligned
// (S*4 % 16 == 0), transpose-stores drop from 8-way to 4-way conflicts.
template <int BM, int BN, int BK>
__global__ __launch_bounds__(128) void k_gemm(const float* __restrict__ A,
                                              const float* __restrict__ B,
                                              float* __restrict__ C, int M, int K) {
  constexpr int TXN = BN / 8;     // threads along N
  constexpr int TYN = 128 / TXN;  // threads along M
  static_assert(BM == TYN * 8, "tile mismatch");
  constexpr int S = BM + 4;
  __shared__ float As[BK][S];
  __shared__ float Bs[BK][BN];
  const int tid = threadIdx.x;
  const int tx = tid % TXN;
  const int ty = tid / TXN;
  const int row0 = blockIdx.x * BM;

  float acc[8][8];
#pragma unroll
  for (int i = 0; i < 8; ++i)
#pragma unroll
    for (int j = 0; j < 8; ++j) acc[i][j] = 0.f;

  for (int k0 = 0; k0 < K; k0 += BK) {
    // ---- stage A tile, transposed into As[k][m] ----
    constexpr int KQ = BK / 4;            // float4 per row
    constexpr int AF4 = BM * BK / 4;
#pragma unroll
    for (int it = 0; it < AF4 / 128; ++it) {
      int v = tid + it * 128;
      int m = v / KQ;
      int kq = v % KQ;
      float4 val = make_float4(0.f, 0.f, 0.f, 0.f);
      if (row0 + m < M)
        val = *(const float4*)(A + (size_t)(row0 + m) * K + k0 + kq * 4);
      As[kq * 4 + 0][m] = val.x;
      As[kq * 4 + 1][m] = val.y;
      As[kq * 4 + 2][m] = val.z;
      As[kq * 4 + 3][m] = val.w;
    }
    // ---- stage B tile: contiguous rows of full-width B ----
    constexpr int BF4 = BK * BN / 4;
    const float4* Bsrc = (const float4*)(B + (size_t)k0 * BN);
    float4* Bdst = (float4*)&Bs[0][0];
#pragma unroll
    for (int it = 0; it < BF4 / 128; ++it)
      Bdst[tid + it * 128] = Bsrc[tid + it * 128];
    __syncthreads();

#pragma unroll
    for (int kk = 0; kk < BK; ++kk) {
      float4 a0 = *(const float4*)&As[kk][ty * 4];
      float4 a1 = *(const float4*)&As[kk][BM / 2 + ty * 4];
      float4 b0 = *(const float4*)&Bs[kk][tx * 4];
      float4 b1 = *(const float4*)&Bs[kk][BN / 2 + tx * 4];
      float av[8] = {a0.x, a0.y, a0.z, a0.w, a1.x, a1.y, a1.z, a1.w};
      float bv[8] = {b0.x, b0.y, b0.z, b0.w, b1.x, b1.y, b1.z, b1.w};
#pragma unroll
      for (int i = 0; i < 8; ++i)
#pragma unroll
        for (int j = 0; j < 8; ++j) acc[i][j] += av[i] * bv[j];
    }
    __syncthreads();
  }

#pragma unroll
  for (int i = 0; i < 8; ++i) {
    int r = row0 + (i < 4 ? ty * 4 + i : BM / 2 + ty * 4 + (i - 4));
    if (r < M) {
      float4 o0 = {acc[i][0], acc[i][1], acc[i][2], acc[i][3]};
      float4 o1 = {acc[i][4], acc[i][5], acc[i][6], acc[i][7]};
      *(float4*)(C + (size_t)r * BN + tx * 4) = o0;
      *(float4*)(C + (size_t)r * BN + BN / 2 + tx * 4) = o1;
    }
  }
}

// Pull aggregation, edge-unrolled x4 (4 independent gather chains).
template <int F, bool RELU>
__global__ __launch_bounds__(F) void k_agg(const float* __restrict__ h,
                                           const float* __restrict__ bias,
                                           const int* __restrict__ row_start,
                                           const int* __restrict__ csr_src,
                                           const float* __restrict__ csr_norm,
                                           const float* __restrict__ dinv,
                                           float* __restrict__ out) {
  int n = blockIdx.x;
  int f = threadIdx.x;
  float dn = dinv[n];
  float acc0 = dn * dn * h[(size_t)n * F + f] + bias[f];
  float acc1 = 0.f, acc2 = 0.f, acc3 = 0.f;
  int e0 = row_start[n], e1 = row_start[n + 1];
  int e = e0;
  for (; e + 4 <= e1; e += 4) {
    int s0 = csr_src[e + 0]; float w0 = csr_norm[e + 0];
    int s1 = csr_src[e + 1]; float w1 = csr_norm[e + 1];
    int s2 = csr_src[e + 2]; float w2 = csr_norm[e + 2];
    int s3 = csr_src[e + 3]; float w3 = csr_norm[e + 3];
    acc0 += w0 * h[(size_t)s0 * F + f];
    acc1 += w1 * h[(size_t)s1 * F + f];
    acc2 += w2 * h[(size_t)s2 * F + f];
    acc3 += w3 * h[(size_t)s3 * F + f];
  }
  for (; e < e1; ++e) {
    int s = csr_src[e];
    acc0 += csr_norm[e] * h[(size_t)s * F + f];
  }
  float acc = (acc0 + acc1) + (acc2 + acc3);
  if (RELU) acc = fmaxf(acc, 0.f);
  out[(size_t)n * F + f] = acc;
}

static inline size_t align256(size_t x) { return (x + 255) & ~(size_t)255; }

extern "C" void kernel_launch(void* const* d_in, const int* in_sizes, int n_in,
                              void* d_out, int out_size, void* d_ws, size_t ws_size,
                              hipStream_t stream) {
  const float* x = (const float*)d_in[0];
  const int* edge = (const int*)d_in[1];
  const float* W1 = (const float*)d_in[2];
  const float* b1 = (const float*)d_in[3];
  const float* W2 = (const float*)d_in[4];
  const float* b2 = (const float*)d_in[5];
  float* out = (float*)d_out;

  const int N = NNODES;
  const int E = NEDGES;
  const int* src = edge;
  const int* dst = edge + E;

  // workspace carve-up
  char* w = (char*)d_ws;
  int* indeg = (int*)w;        w += align256((size_t)N * 4);
  int* cursor = (int*)w;       w += align256((size_t)N * 4);
  float* dinv = (float*)w;     w += align256((size_t)N * 4);
  int* row_start = (int*)w;    w += align256((size_t)(N + 1) * 4);
  int* blocksum = (int*)w;     w += align256(64 * 4);
  int* blockoff = (int*)w;     w += align256(64 * 4);
  int* csr_src = (int*)w;      w += align256((size_t)E * 4);
  float* csr_norm = (float*)w; w += align256((size_t)E * 4);
  float* h0 = (float*)w;       w += align256((size_t)N * NHID * 4);
  float* h1 = (float*)w;       w += align256((size_t)N * NHID * 4);
  float* h2 = (float*)w;       w += align256((size_t)N * NCLS * 4);

  const int nblk_n = (N + 255) / 256;       // 196
  const int nblk_e = (E + 255) / 256;       // 2500
  const int nblk_scan = (N + 1023) / 1024;  // 49

  k_zero2<<<nblk_n, 256, 0, stream>>>(indeg, cursor, N);
  k_hist<<<nblk_e, 256, 0, stream>>>(dst, indeg, E);
  k_dinv<<<nblk_n, 256, 0, stream>>>(indeg, dinv, N);
  k_scan_block<<<nblk_scan, 256, 0, stream>>>(indeg, row_start, blocksum, N);
  k_scan_top<<<1, 64, 0, stream>>>(blocksum, blockoff, nblk_scan);
  k_scan_add<<<nblk_n, 256, 0, stream>>>(row_start, blockoff, N, E);
  k_scatter<<<nblk_e, 256, 0, stream>>>(src, dst, row_start, cursor, dinv,
                                        csr_src, csr_norm, E);

  // GEMM1: h0 = x @ W1   (50000x512 @ 512x128), 782 blocks
  k_gemm<64, NHID, 32><<<(N + 63) / 64, 128, 0, stream>>>(x, W1, h0, N, NFEAT);
  // agg1: h1 = relu(Ahat*h0 + b1)
  k_agg<NHID, true><<<N, NHID, 0, stream>>>(h0, b1, row_start, csr_src, csr_norm,
                                            dinv, h1);
  // GEMM2: h2 = h1 @ W2   (50000x128 @ 128x64), 391 blocks
  k_gemm<128, NCLS, 32><<<(N + 127) / 128, 128, 0, stream>>>(h1, W2, h2, N, NHID);
  // agg2: out = Ahat*h2 + b2
  k_agg<NCLS, false><<<N, NCLS, 0, stream>>>(h2, b2, row_start, csr_src, csr_norm,
                                             dinv, out);
}

// Round 3
// 410.947 us; speedup vs baseline: 1.0987x; 1.0417x over previous
//
#include <hip/hip_runtime.h>

// GCN 2-layer forward for MI355X.
// R3: GEMMs via MFMA fp16-split (hi + lo/1024, 3 products) — no LDS, wave-
// independent 64x64 tiles, A-frag direct global loads, W pre-transposed.
// GEMM1 fuses fp32->fp16split conversion of x; agg1 emits h1 as fp16 pair.

#define NNODES 50000
#define NEDGES 640000
#define NFEAT 512
#define NHID 128
#define NCLS 64

typedef _Float16 f16x8 __attribute__((ext_vector_type(8)));
typedef float f32x4 __attribute__((ext_vector_type(4)));

__global__ void k_zero2(int* __restrict__ a, int* __restrict__ b, int n) {
  int i = blockIdx.x * blockDim.x + threadIdx.x;
  if (i < n) { a[i] = 0; b[i] = 0; }
}

__global__ void k_hist(const int* __restrict__ dst, int* __restrict__ indeg, int E) {
  int i = blockIdx.x * blockDim.x + threadIdx.x;
  if (i < E) atomicAdd(&indeg[dst[i]], 1);
}

__global__ void k_dinv(const int* __restrict__ indeg, float* __restrict__ dinv, int n) {
  int i = blockIdx.x * blockDim.x + threadIdx.x;
  if (i < n) dinv[i] = 1.0f / sqrtf((float)(indeg[i] + 1));
}

__global__ void k_scan_block(const int* __restrict__ indeg, int* __restrict__ row_start,
                             int* __restrict__ blocksum, int n) {
  __shared__ int sdata[256];
  int t = threadIdx.x;
  int base = blockIdx.x * 1024 + t * 4;
  int v[4];
#pragma unroll
  for (int j = 0; j < 4; ++j) v[j] = (base + j < n) ? indeg[base + j] : 0;
  int tsum = v[0] + v[1] + v[2] + v[3];
  sdata[t] = tsum;
  __syncthreads();
  for (int off = 1; off < 256; off <<= 1) {
    int x = (t >= off) ? sdata[t - off] : 0;
    __syncthreads();
    sdata[t] += x;
    __syncthreads();
  }
  int excl = sdata[t] - tsum;
  if (t == 255) blocksum[blockIdx.x] = sdata[255];
  int run = excl;
#pragma unroll
  for (int j = 0; j < 4; ++j) {
    if (base + j < n) { row_start[base + j] = run; run += v[j]; }
  }
}

__global__ void k_scan_top(const int* __restrict__ blocksum, int* __restrict__ blockoff, int nb) {
  if (threadIdx.x == 0 && blockIdx.x == 0) {
    int run = 0;
    for (int i = 0; i < nb; ++i) { blockoff[i] = run; run += blocksum[i]; }
  }
}

__global__ void k_scan_add(int* __restrict__ row_start, const int* __restrict__ blockoff,
                           int n, int E) {
  int i = blockIdx.x * blockDim.x + threadIdx.x;
  if (i < n) row_start[i] += blockoff[i >> 10];
  if (i == 0) row_start[n] = E;
}

__global__ void k_scatter(const int* __restrict__ src, const int* __restrict__ dst,
                          const int* __restrict__ row_start, int* __restrict__ cursor,
                          const float* __restrict__ dinv, int* __restrict__ csr_src,
                          float* __restrict__ csr_norm, int E) {
  int e = blockIdx.x * blockDim.x + threadIdx.x;
  if (e < E) {
    int s = src[e], d = dst[e];
    int pos = atomicAdd(&cursor[d], 1);
    int idx = row_start[d] + pos;
    csr_src[idx] = s;
    csr_norm[idx] = dinv[s] * dinv[d];
  }
}

// W [K][Nc] fp32 -> transposed fp16 split: Wt_hi/Wt_lo [Nc][K], lo pre-scaled 1024.
__global__ void k_wcvt(const float* __restrict__ W, _Float16* __restrict__ Wt_hi,
                       _Float16* __restrict__ Wt_lo, int K, int Nc) {
  int i = blockIdx.x * blockDim.x + threadIdx.x;
  if (i < K * Nc) {
    int k = i / Nc, n = i % Nc;
    float v = W[i];
    _Float16 h = (_Float16)v;
    Wt_hi[(size_t)n * K + k] = h;
    Wt_lo[(size_t)n * K + k] = (_Float16)((v - (float)h) * 1024.0f);
  }
}

// MFMA GEMM: C[M][N] = A[M][K] @ B[K][N], B given transposed-split as
// Bt_hi/Bt_lo [N][K] fp16 (lo pre-scaled by 1024).
// A either fp32 [M][K] (fused split) or fp16 pair [M][K] (lo pre-scaled 1024).
// Block = 4 waves arranged WY x WX, wave tile 64x64, no LDS, no barriers.
// Fragment layout (16x16x32): A row=lane&15, k=(lane>>4)*8+j; B col=lane&15,
// same k; C col=lane&15, row=(lane>>4)*4+reg (m89-verified mapping).
template <int K, int WY, int WX, bool AFP32>
__global__ __launch_bounds__(256) void k_mfma_gemm(
    const float* __restrict__ A32, const _Float16* __restrict__ Ahi,
    const _Float16* __restrict__ Alo, const _Float16* __restrict__ Bhi,
    const _Float16* __restrict__ Blo, float* __restrict__ C, int M, int N) {
  const int wid = threadIdx.x >> 6;
  const int lane = threadIdx.x & 63;
  const int wy = wid / WX, wx = wid % WX;
  const int r0 = (blockIdx.x * WY + wy) * 64;
  const int c0 = (blockIdx.y * WX + wx) * 64;
  const int lrow = lane & 15;
  const int koff = (lane >> 4) * 8;

  f32x4 acc_h[4][4] = {};
  f32x4 acc_l[4][4] = {};

  for (int k0 = 0; k0 < K; k0 += 32) {
    f16x8 bh[4], bl[4];
#pragma unroll
    for (int cf = 0; cf < 4; ++cf) {
      size_t boff = (size_t)(c0 + cf * 16 + lrow) * K + k0 + koff;
      bh[cf] = *(const f16x8*)(Bhi + boff);
      bl[cf] = *(const f16x8*)(Blo + boff);
    }
#pragma unroll
    for (int rf = 0; rf < 4; ++rf) {
      int row = r0 + rf * 16 + lrow;
      row = row < M ? row : M - 1;  // tail frags: load valid garbage, skip store
      f16x8 ah, al;
      if (AFP32) {
        const float* ap = A32 + (size_t)row * K + k0 + koff;
        float4 v0 = *(const float4*)ap;
        float4 v1 = *(const float4*)(ap + 4);
        float vv[8] = {v0.x, v0.y, v0.z, v0.w, v1.x, v1.y, v1.z, v1.w};
#pragma unroll
        for (int j = 0; j < 8; ++j) {
          _Float16 h = (_Float16)vv[j];
          ah[j] = h;
          al[j] = (_Float16)((vv[j] - (float)h) * 1024.0f);
        }
      } else {
        size_t aoff = (size_t)row * K + k0 + koff;
        ah = *(const f16x8*)(Ahi + aoff);
        al = *(const f16x8*)(Alo + aoff);
      }
#pragma unroll
      for (int cf = 0; cf < 4; ++cf) {
        acc_h[rf][cf] =
            __builtin_amdgcn_mfma_f32_16x16x32_f16(ah, bh[cf], acc_h[rf][cf], 0, 0, 0);
        acc_l[rf][cf] =
            __builtin_amdgcn_mfma_f32_16x16x32_f16(ah, bl[cf], acc_l[rf][cf], 0, 0, 0);
        acc_l[rf][cf] =
            __builtin_amdgcn_mfma_f32_16x16x32_f16(al, bh[cf], acc_l[rf][cf], 0, 0, 0);
      }
    }
  }

#pragma unroll
  for (int rf = 0; rf < 4; ++rf) {
    if (r0 + rf * 16 >= M) continue;  // M % 16 == 0: frag all-valid or all-invalid
    int rbase = r0 + rf * 16 + (lane >> 4) * 4;
#pragma unroll
    for (int cf = 0; cf < 4; ++cf) {
      int col = c0 + cf * 16 + lrow;
#pragma unroll
      for (int q = 0; q < 4; ++q) {
        C[(size_t)(rbase + q) * N + col] =
            acc_h[rf][cf][q] + acc_l[rf][cf][q] * (1.0f / 1024.0f);
      }
    }
  }
}

// Pull aggregation, edge-unrolled x4. Optionally emit fp16 split pair
// (lo pre-scaled 1024) for the next MFMA GEMM.
template <int F, bool RELU, bool EMIT16>
__global__ __launch_bounds__(F) void k_agg(const float* __restrict__ h,
                                           const float* __restrict__ bias,
                                           const int* __restrict__ row_start,
                                           const int* __restrict__ csr_src,
                                           const float* __restrict__ csr_norm,
                                           const float* __restrict__ dinv,
                                           float* __restrict__ out,
                                           _Float16* __restrict__ out_hi,
                                           _Float16* __restrict__ out_lo) {
  int n = blockIdx.x;
  int f = threadIdx.x;
  float dn = dinv[n];
  float acc0 = dn * dn * h[(size_t)n * F + f] + bias[f];
  float acc1 = 0.f, acc2 = 0.f, acc3 = 0.f;
  int e0 = row_start[n], e1 = row_start[n + 1];
  int e = e0;
  for (; e + 4 <= e1; e += 4) {
    int s0 = csr_src[e + 0]; float w0 = csr_norm[e + 0];
    int s1 = csr_src[e + 1]; float w1 = csr_norm[e + 1];
    int s2 = csr_src[e + 2]; float w2 = csr_norm[e + 2];
    int s3 = csr_src[e + 3]; float w3 = csr_norm[e + 3];
    acc0 += w0 * h[(size_t)s0 * F + f];
    acc1 += w1 * h[(size_t)s1 * F + f];
    acc2 += w2 * h[(size_t)s2 * F + f];
    acc3 += w3 * h[(size_t)s3 * F + f];
  }
  for (; e < e1; ++e) {
    int s = csr_src[e];
    acc0 += csr_norm[e] * h[(size_t)s * F + f];
  }
  float acc = (acc0 + acc1) + (acc2 + acc3);
  if (RELU) acc = fmaxf(acc, 0.f);
  if (EMIT16) {
    _Float16 hh = (_Float16)acc;
    out_hi[(size_t)n * F + f] = hh;
    out_lo[(size_t)n * F + f] = (_Float16)((acc - (float)hh) * 1024.0f);
  } else {
    out[(size_t)n * F + f] = acc;
  }
}

static inline size_t align256(size_t x) { return (x + 255) & ~(size_t)255; }

extern "C" void kernel_launch(void* const* d_in, const int* in_sizes, int n_in,
                              void* d_out, int out_size, void* d_ws, size_t ws_size,
                              hipStream_t stream) {
  const float* x = (const float*)d_in[0];
  const int* edge = (const int*)d_in[1];
  const float* W1 = (const float*)d_in[2];
  const float* b1 = (const float*)d_in[3];
  const float* W2 = (const float*)d_in[4];
  const float* b2 = (const float*)d_in[5];
  float* out = (float*)d_out;

  const int N = NNODES;
  const int E = NEDGES;
  const int* src = edge;
  const int* dst = edge + E;

  // workspace carve-up
  char* w = (char*)d_ws;
  int* indeg = (int*)w;          w += align256((size_t)N * 4);
  int* cursor = (int*)w;         w += align256((size_t)N * 4);
  float* dinv = (float*)w;       w += align256((size_t)N * 4);
  int* row_start = (int*)w;      w += align256((size_t)(N + 1) * 4);
  int* blocksum = (int*)w;       w += align256(64 * 4);
  int* blockoff = (int*)w;       w += align256(64 * 4);
  int* csr_src = (int*)w;        w += align256((size_t)E * 4);
  float* csr_norm = (float*)w;   w += align256((size_t)E * 4);
  _Float16* W1t_hi = (_Float16*)w; w += align256((size_t)NFEAT * NHID * 2);
  _Float16* W1t_lo = (_Float16*)w; w += align256((size_t)NFEAT * NHID * 2);
  _Float16* W2t_hi = (_Float16*)w; w += align256((size_t)NHID * NCLS * 2);
  _Float16* W2t_lo = (_Float16*)w; w += align256((size_t)NHID * NCLS * 2);
  float* h0 = (float*)w;         w += align256((size_t)N * NHID * 4);
  _Float16* h1_hi = (_Float16*)w; w += align256((size_t)N * NHID * 2);
  _Float16* h1_lo = (_Float16*)w; w += align256((size_t)N * NHID * 2);
  float* h2 = (float*)w;         w += align256((size_t)N * NCLS * 4);

  const int nblk_n = (N + 255) / 256;
  const int nblk_e = (E + 255) / 256;
  const int nblk_scan = (N + 1023) / 1024;

  k_zero2<<<nblk_n, 256, 0, stream>>>(indeg, cursor, N);
  k_hist<<<nblk_e, 256, 0, stream>>>(dst, indeg, E);
  k_dinv<<<nblk_n, 256, 0, stream>>>(indeg, dinv, N);
  k_scan_block<<<nblk_scan, 256, 0, stream>>>(indeg, row_start, blocksum, N);
  k_scan_top<<<1, 64, 0, stream>>>(blocksum, blockoff, nblk_scan);
  k_scan_add<<<nblk_n, 256, 0, stream>>>(row_start, blockoff, N, E);
  k_scatter<<<nblk_e, 256, 0, stream>>>(src, dst, row_start, cursor, dinv,
                                        csr_src, csr_norm, E);

  // Weight transpose+split (tiny)
  k_wcvt<<<(NFEAT * NHID + 255) / 256, 256, 0, stream>>>(W1, W1t_hi, W1t_lo,
                                                         NFEAT, NHID);
  k_wcvt<<<(NHID * NCLS + 255) / 256, 256, 0, stream>>>(W2, W2t_hi, W2t_lo,
                                                        NHID, NCLS);

  // GEMM1: h0 = x @ W1  (fused fp32->fp16 split on A). Block tile 128x128.
  {
    dim3 grid((N + 127) / 128, 1);
    k_mfma_gemm<NFEAT, 2, 2, true><<<grid, 256, 0, stream>>>(
        x, nullptr, nullptr, W1t_hi, W1t_lo, h0, N, NHID);
  }
  // agg1: h1 = relu(Ahat*h0 + b1), emitted as fp16 split pair
  k_agg<NHID, true, true><<<N, NHID, 0, stream>>>(h0, b1, row_start, csr_src,
                                                  csr_norm, dinv, nullptr,
                                                  h1_hi, h1_lo);
  // GEMM2: h2 = h1 @ W2 (A already fp16 pair). Block tile 256x64.
  {
    dim3 grid((N + 255) / 256, 1);
    k_mfma_gemm<NHID, 4, 1, false><<<grid, 256, 0, stream>>>(
        nullptr, h1_hi, h1_lo, W2t_hi, W2t_lo, h2, N, NCLS);
  }
  // agg2: out = Ahat*h2 + b2
  k_agg<NCLS, false, false><<<N, NCLS, 0, stream>>>(h2, b2, row_start, csr_src,
                                                    csr_norm, dinv, out,
                                                    nullptr, nullptr);
}